// Round 13
// baseline (303.931 us; speedup 1.0000x reference)
//
#include <hip/hip_runtime.h>
#include <math.h>

#define N_PIX 32768
#define DEG 9
#define BATCH 8
#define TILE 64

typedef unsigned short u16;
typedef __attribute__((ext_vector_type(8))) short bf16x8;
typedef __attribute__((ext_vector_type(16))) float f32x16;

__device__ __forceinline__ u16 bf16_rn(float x) {
    unsigned int u = __builtin_bit_cast(unsigned int, x);
    u += 0x7fffu + ((u >> 16) & 1u);
    return (u16)(u >> 16);
}
__device__ __forceinline__ float bf16_to_f(u16 u) {
    unsigned int v = ((unsigned int)u) << 16;
    return __builtin_bit_cast(float, v);
}

// Row-rotation swizzled LDS plane addressing, LD=64:
//   element (row, c) at row*64 + ((c + 8*(row&7)) & 63)
// Pure within-row permutation (rotation multiple of 8 -> float4 groups intact,
// 16B aligned). Scatter banks: 8*((q+row)&7) pattern -> 2-way max (free, m136).
__device__ __forceinline__ int rot(int row, int c) {
    return row * 64 + ((c + ((row & 7) << 3)) & 63);
}

// Activation planes (split-bf16 hi/lo) chunked GLOBAL layout:
//   (row g, ch c) -> (g>>5)*2048 + (c>>3)*256 + (g&31)*8 + (c&7)
// so a GEMM B-fragment (32 rows x 8 ch) is one coalesced dwordx4 load.

// ---------------------------------------------------------------------------
// Prep, single launch, grid (13,16):
//  bx 0-2 : mid-layer weight frags (layout verified R2-R12)
//  bx 3   : first-layer frags at u16 offset 73728 (K padded 8->16)
//  bx 5-12: Vpre[32768][12] padded stencil-coeff table (pure copy of vals)
// ---------------------------------------------------------------------------
__global__ void prep_all(const float* __restrict__ W1, const float* __restrict__ W2,
                         const float* __restrict__ W3, const float* __restrict__ W4,
                         const float* __restrict__ vals,
                         u16* __restrict__ out, float* __restrict__ vpre) {
    if (blockIdx.x < 3) {
        const float* W = (blockIdx.x == 0) ? W2 : (blockIdx.x == 1) ? W3 : W4;
        u16* o = out + (size_t)blockIdx.x * 24576;
        const int base = blockIdx.y * 768;
        for (int idx = base + threadIdx.x; idx < base + 768; idx += 256) {
            int j = idx & 7;
            int lane = (idx >> 3) & 63;
            int rest = idx >> 9;
            int s = rest & 3, tt = rest >> 2;
            int mt = tt & 1, mat = tt >> 1;
            int k = s * 16 + (lane >> 5) * 8 + j;
            int m = mt * 32 + (lane & 31);
            float x = (mat == 0) ? W[k * 64 + m] - W[(128 + k) * 64 + m]
                    : (mat == 1) ? W[(64 + k) * 64 + m]
                                 : W[(128 + k) * 64 + m];
            u16 hi = bf16_rn(x);
            o[idx] = hi;
            o[12288 + idx] = bf16_rn(x - bf16_to_f(hi));
        }
    } else if (blockIdx.x == 3) {
        u16* o = out + 73728;
        const int base = blockIdx.y * 1536;
        for (int e = base + threadIdx.x; e < base + 1536 && e < 24576; e += 256) {
            int j = e & 7;
            int lane = (e >> 3) & 63;
            int tt = e >> 12;
            int mt = tt & 1, mat = tt >> 1;
            int m = mt * 32 + (lane & 31);
            float x = 0.f;
            if ((lane >> 5) == 0) {
                x = (mat == 0) ? W1[j * 64 + m] - W1[(16 + j) * 64 + m]
                  : (mat == 1) ? W1[(8 + j) * 64 + m]
                               : W1[(16 + j) * 64 + m];
            }
            u16 hi = bf16_rn(x);
            o[e] = hi;
            o[24576 + e] = bf16_rn(x - bf16_to_f(hi));
        }
    } else if (blockIdx.x >= 5) {
        const int vb = (blockIdx.x - 5) * 16 + blockIdx.y;   // 0..127
        const int base = vb * 3072;
        #pragma unroll
        for (int k = 0; k < 12; ++k) {
            int idx = base + k * 256 + threadIdx.x;
            int g = idx / 12, j = idx - g * 12;
            vpre[idx] = (j < 9) ? vals[(size_t)g * 9 + j] : 0.f;
        }
    }
}

// ---------------------------------------------------------------------------
// Fused ChebConv layer (R9/R12 numerics; 4 blocks/CU): LD=64 row-rotation
// planes, coefficients read directly from global Vpre (no Vs LDS buffer).
// LDS = 38,912 B. P0 GEMM co-scheduled with stencil1 (verified R9).
// ---------------------------------------------------------------------------
template<bool FIRST>
__global__ __launch_bounds__(512, 8)
void cheb_conv(const float* __restrict__ Xf, const u16* __restrict__ Xh,
               const u16* __restrict__ Xl, const float* __restrict__ Vpre,
               const u16* __restrict__ wt, int wbase, const float* __restrict__ bias,
               u16* __restrict__ Yh, u16* __restrict__ Yl) {
    __shared__ alignas(16) float P2s[80 * 64];   // P2; after stencil1: P0 (rows 0..63)
    __shared__ alignas(16) float P1s[72 * 64];   // P1 -> S (in place)

    const int tid = threadIdx.x;
    // XCD-contiguous swizzle (verified R8: FETCH 42->33.7 MB)
    const int bx = ((blockIdx.x & 7) << 6) | (blockIdx.x >> 3);
    const int n0 = bx * TILE;
    const int b  = blockIdx.y;
    const size_t bplane = (size_t)b * ((size_t)N_PIX * 64);

    const int w = tid >> 6, lane = tid & 63;
    const int half = lane >> 5, m31 = lane & 31;

    // GEMM compute (verified R8-R12): D = M^T X^T, dual-m accumulators
    auto gemm_accs = [&](int mat, int rowoff, int rl, f32x16& acc0, f32x16& acc1) {
        const int g = (n0 + rowoff + rl) & (N_PIX - 1);
        constexpr int SC   = FIRST ? 1 : 4;
        constexpr int LOFF = FIRST ? 24576 : 12288;
        const u16* a0p = wt + wbase + lane * 8 + (FIRST ? (mat * 2) * 4096 : mat * 4096);
        const u16* a1p = a0p + (FIRST ? 4096 : 2048);
        const size_t bbase = bplane + (size_t)(g >> 5) * 2048 + (size_t)(g & 31) * 8;
        const float* xfp = FIRST ? (Xf + (size_t)b * N_PIX * 8 + (size_t)g * 8) : nullptr;
        #pragma unroll
        for (int s = 0; s < SC; ++s) {
            bf16x8 bh = {}, bl = {};
            if constexpr (FIRST) {
                if (half == 0) {
                    float xv[8];
                    *(float4*)&xv[0] = *(const float4*)&xfp[0];
                    *(float4*)&xv[4] = *(const float4*)&xfp[4];
                    #pragma unroll
                    for (int e = 0; e < 8; ++e) {
                        u16 hh = bf16_rn(xv[e]);
                        bh[e] = (short)hh;
                        bl[e] = (short)bf16_rn(xv[e] - bf16_to_f(hh));
                    }
                }
            } else {
                const size_t off = bbase + (size_t)(s * 2 + half) * 256;
                bh = *(const bf16x8*)&Xh[off];
                bl = *(const bf16x8*)&Xl[off];
            }
            bf16x8 a0h = *(const bf16x8*)(a0p + s * 512);
            bf16x8 a0l = *(const bf16x8*)(a0p + s * 512 + LOFF);
            bf16x8 a1h = *(const bf16x8*)(a1p + s * 512);
            bf16x8 a1l = *(const bf16x8*)(a1p + s * 512 + LOFF);
            acc0 = __builtin_amdgcn_mfma_f32_32x32x16_bf16(a0l, bh, acc0, 0, 0, 0);
            acc0 = __builtin_amdgcn_mfma_f32_32x32x16_bf16(a0h, bl, acc0, 0, 0, 0);
            acc0 = __builtin_amdgcn_mfma_f32_32x32x16_bf16(a0h, bh, acc0, 0, 0, 0);
            acc1 = __builtin_amdgcn_mfma_f32_32x32x16_bf16(a1l, bh, acc1, 0, 0, 0);
            acc1 = __builtin_amdgcn_mfma_f32_32x32x16_bf16(a1h, bl, acc1, 0, 0, 0);
            acc1 = __builtin_amdgcn_mfma_f32_32x32x16_bf16(a1h, bh, acc1, 0, 0, 0);
        }
    };
    // scatter: lane = row rl, regs 4q..4q+3 = ch q*8+half*4 .. +3 (rotated)
    auto scatter = [&](float* dst, int rl, const f32x16& a0, const f32x16& a1) {
        #pragma unroll
        for (int q = 0; q < 4; ++q) {
            float4 v0 = {a0[4 * q], a0[4 * q + 1], a0[4 * q + 2], a0[4 * q + 3]};
            float4 v1 = {a1[4 * q], a1[4 * q + 1], a1[4 * q + 2], a1[4 * q + 3]};
            *(float4*)&dst[rot(rl, q * 8 + half * 4)]      = v0;
            *(float4*)&dst[rot(rl, 32 + q * 8 + half * 4)] = v1;
        }
    };

    // ---- phase 1: P2 (waves 0-2) and P1 (waves 3-5) GEMMs ----
    if (w < 6) {
        int mat, ntile, rowoff; float* dst;
        if (w < 3) { mat = 2; ntile = (w == 0) ? 0 : ((w == 1) ? 32 : 48); rowoff = -8; dst = P2s; }
        else       { mat = 1; ntile = (w == 3) ? 0 : ((w == 4) ? 32 : 40); rowoff = -4; dst = P1s; }
        f32x16 acc0 = {}, acc1 = {};
        gemm_accs(mat, rowoff, ntile + m31, acc0, acc1);
        scatter(dst, ntile + m31, acc0, acc1);
    }
    __syncthreads();

    // ---- phase 2: stencil1 (VALU, waves 0-5) || P0 GEMM (MFMA, waves 6-7) ----
    f32x16 pacc0 = {}, pacc1 = {};
    int prl = 0;
    if (tid < 384) {
        // stencil1: S = P1 + 2 L P2, in place on P1s, strips of 3
        const int st = tid >> 4, c0 = (tid & 15) << 2;
        const int r0 = st * 3;
        float4 win[11];
        #pragma unroll
        for (int l = 0; l < 11; ++l)
            win[l] = *(const float4*)&P2s[rot(r0 + l, c0)];
        #pragma unroll
        for (int r = 0; r < 3; ++r) {
            const int sg = r0 + r;
            const float* vp = &Vpre[(size_t)((n0 - 4 + sg) & (N_PIX - 1)) * 12];
            float4 vA = *(const float4*)vp;
            float4 vB = *(const float4*)(vp + 4);
            float v8 = vp[8];
            const float vj[9] = {vA.x, vA.y, vA.z, vA.w, vB.x, vB.y, vB.z, vB.w, v8};
            float4 a = {0.f, 0.f, 0.f, 0.f};
            #pragma unroll
            for (int j = 0; j < 9; ++j) {
                float4 xv = win[r + j];
                a.x = fmaf(vj[j], xv.x, a.x); a.y = fmaf(vj[j], xv.y, a.y);
                a.z = fmaf(vj[j], xv.z, a.z); a.w = fmaf(vj[j], xv.w, a.w);
            }
            float4 p1 = *(const float4*)&P1s[rot(sg, c0)];
            p1.x = fmaf(2.f, a.x, p1.x); p1.y = fmaf(2.f, a.y, p1.y);
            p1.z = fmaf(2.f, a.z, p1.z); p1.w = fmaf(2.f, a.w, p1.w);
            *(float4*)&P1s[rot(sg, c0)] = p1;
        }
    } else {
        prl = ((w == 6) ? 0 : 32) + m31;
        gemm_accs(0, 0, prl, pacc0, pacc1);
    }
    __syncthreads();

    // ---- phase 3: P0 scatter into P2s (now dead) ----
    if (tid >= 384) scatter(P2s, prl, pacc0, pacc1);
    __syncthreads();

    // ---- phase 4: stencil2 + epilogue: Y = elu(P0 + L S + b) ----
    {
        const int est = tid >> 4, ecx = tid & 15;
        const int ey0 = est * 2, ec0 = ecx << 2;
        float4 win[10];
        #pragma unroll
        for (int l = 0; l < 10; ++l)
            win[l] = *(const float4*)&P1s[rot(ey0 + l, ec0)];
        const float4 bb = *(const float4*)&bias[ec0];
        #pragma unroll
        for (int r = 0; r < 2; ++r) {
            const int y = ey0 + r;
            const float* vp = &Vpre[(size_t)((n0 + y) & (N_PIX - 1)) * 12];
            float4 vA = *(const float4*)vp;
            float4 vB = *(const float4*)(vp + 4);
            float v8 = vp[8];
            const float vj[9] = {vA.x, vA.y, vA.z, vA.w, vB.x, vB.y, vB.z, vB.w, v8};
            float4 a = bb;
            #pragma unroll
            for (int j = 0; j < 9; ++j) {
                float4 xv = win[r + j];
                a.x = fmaf(vj[j], xv.x, a.x); a.y = fmaf(vj[j], xv.y, a.y);
                a.z = fmaf(vj[j], xv.z, a.z); a.w = fmaf(vj[j], xv.w, a.w);
            }
            float4 p0 = *(const float4*)&P2s[rot(y, ec0)];
            float yv[4] = {a.x + p0.x, a.y + p0.y, a.z + p0.z, a.w + p0.w};
            ushort4 h, l;
            u16 hh;
            #pragma unroll
            for (int e = 0; e < 4; ++e)
                yv[e] = yv[e] > 0.f ? yv[e] : __expf(yv[e]) - 1.f;
            hh = bf16_rn(yv[0]); h.x = hh; l.x = bf16_rn(yv[0] - bf16_to_f(hh));
            hh = bf16_rn(yv[1]); h.y = hh; l.y = bf16_rn(yv[1] - bf16_to_f(hh));
            hh = bf16_rn(yv[2]); h.z = hh; l.z = bf16_rn(yv[2] - bf16_to_f(hh));
            hh = bf16_rn(yv[3]); h.w = hh; l.w = bf16_rn(yv[3] - bf16_to_f(hh));
            const int gy = n0 + y;
            size_t dsto = bplane + (size_t)(gy >> 5) * 2048 + (size_t)(ecx >> 1) * 256
                        + (size_t)(gy & 31) * 8 + (size_t)(ecx & 1) * 4;
            *(ushort4*)&Yh[dsto] = h;
            *(ushort4*)&Yl[dsto] = l;
        }
    }
}

// ---------------------------------------------------------------------------
// Last layer, 128 rows/block (verified R12).
// ---------------------------------------------------------------------------
__global__ __launch_bounds__(512, 4)
void cheb_last4(const u16* __restrict__ Xh, const u16* __restrict__ Xl,
                const float* __restrict__ vals,
                const float* __restrict__ W5, const float* __restrict__ b5,
                float* __restrict__ Y) {
    __shared__ alignas(16) float Pb[144 * 8];
    __shared__ alignas(16) float Sb[136 * 2];
    __shared__ alignas(16) float Vs[136 * 12];

    const int tid = threadIdx.x;
    const int n0 = blockIdx.x * 128;
    const int b  = blockIdx.y;
    const size_t bplane = (size_t)b * ((size_t)N_PIX * 64);

    for (int i = tid; i < 1224; i += 512) {
        int sr = i / 9, j = i - sr * 9;
        int g = (n0 - 4 + sr) & (N_PIX - 1);
        Vs[sr * 12 + j] = vals[(size_t)g * DEG + j];
    }

    {
        const int w = tid >> 6, lane = tid & 63;
        const int half = lane >> 5, m31 = lane & 31;
        if (w < 5) {
            const int ntile = (w == 4) ? 112 : w * 32;
            const int rl = ntile + m31;
            const int g = (n0 - 8 + rl) & (N_PIX - 1);
            const size_t bbase = bplane + (size_t)(g >> 5) * 2048 + (g & 31) * 8;
            const bool valid = m31 < 6;
            const int seg = m31 >> 1, o = m31 & 1;
            f32x16 acc = {};
            #pragma unroll
            for (int s = 0; s < 4; ++s) {
                const size_t off = bbase + (size_t)(s * 2 + half) * 256;
                bf16x8 bh = *(const bf16x8*)&Xh[off];
                bf16x8 bl = *(const bf16x8*)&Xl[off];
                bf16x8 ah, al;
                #pragma unroll
                for (int j = 0; j < 8; ++j) {
                    int k = s * 16 + half * 8 + j;
                    float x = valid ? W5[(seg * 64 + k) * 2 + o] : 0.f;
                    u16 hh = bf16_rn(x);
                    ah[j] = (short)hh;
                    al[j] = (short)bf16_rn(x - bf16_to_f(hh));
                }
                acc = __builtin_amdgcn_mfma_f32_32x32x16_bf16(al, bh, acc, 0, 0, 0);
                acc = __builtin_amdgcn_mfma_f32_32x32x16_bf16(ah, bl, acc, 0, 0, 0);
                acc = __builtin_amdgcn_mfma_f32_32x32x16_bf16(ah, bh, acc, 0, 0, 0);
            }
            if (half == 0) {
                float4 v = {acc[0], acc[1], acc[2], acc[3]};
                *(float4*)&Pb[rl * 8] = v;
            } else {
                Pb[rl * 8 + 4] = acc[0];
                Pb[rl * 8 + 5] = acc[1];
            }
        }
    }
    __syncthreads();

    if (tid < 272) {
        const int sg = tid >> 1, o = tid & 1;
        float q = 0.f;
        #pragma unroll
        for (int j = 0; j < DEG; ++j)
            q = fmaf(Vs[sg * 12 + j], Pb[(sg + j) * 8 + 4 + o], q);
        Sb[sg * 2 + o] = Pb[(sg + 4) * 8 + 2 + o] + 2.f * q;
    }
    __syncthreads();

    if (tid < 256) {
        const int y = tid >> 1, o = tid & 1;
        float q = 0.f;
        #pragma unroll
        for (int j = 0; j < DEG; ++j)
            q = fmaf(Vs[(y + 4) * 12 + j], Sb[(y + j) * 2 + o], q);
        float v = Pb[(y + 8) * 8 + o] - Pb[(y + 8) * 8 + 4 + o] + q + b5[o];
        Y[((size_t)b * N_PIX + n0 + y) * 2 + o] = v;
    }
}

extern "C" void kernel_launch(void* const* d_in, const int* in_sizes, int n_in,
                              void* d_out, int out_size, void* d_ws, size_t ws_size,
                              hipStream_t stream) {
    const float* x    = (const float*)d_in[0];
    const float* vals = (const float*)d_in[3];
    const float* W1 = (const float*)d_in[4];
    const float* b1 = (const float*)d_in[5];
    const float* W2 = (const float*)d_in[6];
    const float* b2 = (const float*)d_in[7];
    const float* W3 = (const float*)d_in[8];
    const float* b3 = (const float*)d_in[9];
    const float* W4 = (const float*)d_in[10];
    const float* b4 = (const float*)d_in[11];
    const float* W5 = (const float*)d_in[12];
    const float* b5 = (const float*)d_in[13];
    float* out = (float*)d_out;

    const size_t PL = (size_t)BATCH * N_PIX * 64;
    u16* Ah_g = (u16*)d_ws;
    u16* Al_g = Ah_g + PL;
    u16* Bh_g = Ah_g + 2 * PL;
    u16* Bl_g = Ah_g + 3 * PL;
    // d_out scratch: weight frags [0, 246 KiB) + Vpre at byte 262144
    // (1.57 MiB) -> 1.83 MiB < 2 MiB; all consumed before cheb_last4
    // overwrites d_out with Y.
    u16* wt = (u16*)d_out;
    float* vpre = (float*)((char*)d_out + 262144);

    dim3 grid(N_PIX / TILE, BATCH);
    prep_all<<<dim3(13, 16), dim3(256), 0, stream>>>(W1, W2, W3, W4, vals, wt, vpre);
    cheb_conv<true><<<grid, dim3(512), 0, stream>>>(x, nullptr, nullptr, vpre, wt, 73728, b1, Ah_g, Al_g);
    cheb_conv<false><<<grid, dim3(512), 0, stream>>>(nullptr, Ah_g, Al_g, vpre, wt, 0,     b2, Bh_g, Bl_g);
    cheb_conv<false><<<grid, dim3(512), 0, stream>>>(nullptr, Bh_g, Bl_g, vpre, wt, 24576, b3, Ah_g, Al_g);
    cheb_conv<false><<<grid, dim3(512), 0, stream>>>(nullptr, Ah_g, Al_g, vpre, wt, 49152, b4, Bh_g, Bl_g);
    cheb_last4<<<dim3(N_PIX / 128, BATCH), dim3(512), 0, stream>>>(Bh_g, Bl_g, vals, W5, b5, out);
}

// Round 14
// 290.925 us; speedup vs baseline: 1.0447x; 1.0447x over previous
//
#include <hip/hip_runtime.h>
#include <math.h>

#define N_PIX 32768
#define DEG 9
#define BATCH 8
#define TILE 64

typedef unsigned short u16;
typedef __attribute__((ext_vector_type(8))) short bf16x8;
typedef __attribute__((ext_vector_type(16))) float f32x16;

__device__ __forceinline__ u16 bf16_rn(float x) {
    unsigned int u = __builtin_bit_cast(unsigned int, x);
    u += 0x7fffu + ((u >> 16) & 1u);
    return (u16)(u >> 16);
}
__device__ __forceinline__ float bf16_to_f(u16 u) {
    unsigned int v = ((unsigned int)u) << 16;
    return __builtin_bit_cast(float, v);
}

// Activation planes (split-bf16 hi/lo) chunked GLOBAL layout:
//   (row g, ch c) -> (g>>5)*2048 + (c>>3)*256 + (g&31)*8 + (c&7)
// so a GEMM B-fragment (32 rows x 8 ch) is one coalesced dwordx4 load.

// ---------------------------------------------------------------------------
// Prep, single launch, grid (13,16):
//  bx 0-2 : mid-layer weight frags (layout verified R2-R12)
//  bx 3   : first-layer frags at u16 offset 73728 (K padded 8->16)
//  bx 5-12: Vpre[32768][12] padded stencil-coeff table (pure copy of vals)
// ---------------------------------------------------------------------------
__global__ void prep_all(const float* __restrict__ W1, const float* __restrict__ W2,
                         const float* __restrict__ W3, const float* __restrict__ W4,
                         const float* __restrict__ vals,
                         u16* __restrict__ out, float* __restrict__ vpre) {
    if (blockIdx.x < 3) {
        const float* W = (blockIdx.x == 0) ? W2 : (blockIdx.x == 1) ? W3 : W4;
        u16* o = out + (size_t)blockIdx.x * 24576;
        const int base = blockIdx.y * 768;
        for (int idx = base + threadIdx.x; idx < base + 768; idx += 256) {
            int j = idx & 7;
            int lane = (idx >> 3) & 63;
            int rest = idx >> 9;
            int s = rest & 3, tt = rest >> 2;
            int mt = tt & 1, mat = tt >> 1;
            int k = s * 16 + (lane >> 5) * 8 + j;
            int m = mt * 32 + (lane & 31);
            float x = (mat == 0) ? W[k * 64 + m] - W[(128 + k) * 64 + m]
                    : (mat == 1) ? W[(64 + k) * 64 + m]
                                 : W[(128 + k) * 64 + m];
            u16 hi = bf16_rn(x);
            o[idx] = hi;
            o[12288 + idx] = bf16_rn(x - bf16_to_f(hi));
        }
    } else if (blockIdx.x == 3) {
        u16* o = out + 73728;
        const int base = blockIdx.y * 1536;
        for (int e = base + threadIdx.x; e < base + 1536 && e < 24576; e += 256) {
            int j = e & 7;
            int lane = (e >> 3) & 63;
            int tt = e >> 12;
            int mt = tt & 1, mat = tt >> 1;
            int m = mt * 32 + (lane & 31);
            float x = 0.f;
            if ((lane >> 5) == 0) {
                x = (mat == 0) ? W1[j * 64 + m] - W1[(16 + j) * 64 + m]
                  : (mat == 1) ? W1[(8 + j) * 64 + m]
                               : W1[(16 + j) * 64 + m];
            }
            u16 hi = bf16_rn(x);
            o[e] = hi;
            o[24576 + e] = bf16_rn(x - bf16_to_f(hi));
        }
    } else if (blockIdx.x >= 5) {
        const int vb = (blockIdx.x - 5) * 16 + blockIdx.y;   // 0..127
        const int base = vb * 3072;
        #pragma unroll
        for (int k = 0; k < 12; ++k) {
            int idx = base + k * 256 + threadIdx.x;
            int g = idx / 12, j = idx - g * 12;
            vpre[idx] = (j < 9) ? vals[(size_t)g * 9 + j] : 0.f;
        }
    }
}

// ---------------------------------------------------------------------------
// Fused ChebConv layer (exact R12 structure/numerics, LD=68, 3 blocks/CU):
// P0 GEMM co-scheduled with stencil1; Vs from prepped Vpre (float4 copies).
// ---------------------------------------------------------------------------
template<bool FIRST>
__global__ __launch_bounds__(512, 6)
void cheb_conv(const float* __restrict__ Xf, const u16* __restrict__ Xh,
               const u16* __restrict__ Xl, const float* __restrict__ Vpre,
               const u16* __restrict__ wt, int wbase, const float* __restrict__ bias,
               u16* __restrict__ Yh, u16* __restrict__ Yl) {
    constexpr int LD = 68;
    __shared__ alignas(16) float P2s[80 * LD];   // P2; after stencil1: P0 (rows 0..63)
    __shared__ alignas(16) float P1s[72 * LD];   // P1 -> S (in place)
    __shared__ alignas(16) float Vs[72 * 12];

    const int tid = threadIdx.x;
    // XCD-contiguous swizzle (verified R8: FETCH 42->33.7 MB)
    const int bx = ((blockIdx.x & 7) << 6) | (blockIdx.x >> 3);
    const int n0 = bx * TILE;
    const int b  = blockIdx.y;
    const size_t bplane = (size_t)b * ((size_t)N_PIX * 64);

    // Vs rows n0-4..n0+67 as float4 copies from the padded table
    if (tid < 216) {
        int r = tid / 3, q = tid - r * 3;
        int g = (n0 - 4 + r) & (N_PIX - 1);
        *(float4*)&Vs[r * 12 + q * 4] = *(const float4*)&Vpre[(size_t)g * 12 + q * 4];
    }

    const int w = tid >> 6, lane = tid & 63;
    const int half = lane >> 5, m31 = lane & 31;

    // GEMM compute (verified R8-R12): D = M^T X^T, dual-m accumulators
    auto gemm_accs = [&](int mat, int rowoff, int rl, f32x16& acc0, f32x16& acc1) {
        const int g = (n0 + rowoff + rl) & (N_PIX - 1);
        constexpr int SC   = FIRST ? 1 : 4;
        constexpr int LOFF = FIRST ? 24576 : 12288;
        const u16* a0p = wt + wbase + lane * 8 + (FIRST ? (mat * 2) * 4096 : mat * 4096);
        const u16* a1p = a0p + (FIRST ? 4096 : 2048);
        const size_t bbase = bplane + (size_t)(g >> 5) * 2048 + (size_t)(g & 31) * 8;
        const float* xfp = FIRST ? (Xf + (size_t)b * N_PIX * 8 + (size_t)g * 8) : nullptr;
        #pragma unroll
        for (int s = 0; s < SC; ++s) {
            bf16x8 bh = {}, bl = {};
            if constexpr (FIRST) {
                if (half == 0) {
                    float xv[8];
                    *(float4*)&xv[0] = *(const float4*)&xfp[0];
                    *(float4*)&xv[4] = *(const float4*)&xfp[4];
                    #pragma unroll
                    for (int e = 0; e < 8; ++e) {
                        u16 hh = bf16_rn(xv[e]);
                        bh[e] = (short)hh;
                        bl[e] = (short)bf16_rn(xv[e] - bf16_to_f(hh));
                    }
                }
            } else {
                const size_t off = bbase + (size_t)(s * 2 + half) * 256;
                bh = *(const bf16x8*)&Xh[off];
                bl = *(const bf16x8*)&Xl[off];
            }
            bf16x8 a0h = *(const bf16x8*)(a0p + s * 512);
            bf16x8 a0l = *(const bf16x8*)(a0p + s * 512 + LOFF);
            bf16x8 a1h = *(const bf16x8*)(a1p + s * 512);
            bf16x8 a1l = *(const bf16x8*)(a1p + s * 512 + LOFF);
            acc0 = __builtin_amdgcn_mfma_f32_32x32x16_bf16(a0l, bh, acc0, 0, 0, 0);
            acc0 = __builtin_amdgcn_mfma_f32_32x32x16_bf16(a0h, bl, acc0, 0, 0, 0);
            acc0 = __builtin_amdgcn_mfma_f32_32x32x16_bf16(a0h, bh, acc0, 0, 0, 0);
            acc1 = __builtin_amdgcn_mfma_f32_32x32x16_bf16(a1l, bh, acc1, 0, 0, 0);
            acc1 = __builtin_amdgcn_mfma_f32_32x32x16_bf16(a1h, bl, acc1, 0, 0, 0);
            acc1 = __builtin_amdgcn_mfma_f32_32x32x16_bf16(a1h, bh, acc1, 0, 0, 0);
        }
    };
    // scatter: lane = row rl, regs 4q..4q+3 = ch q*8+half*4 .. +3
    auto scatter = [&](float* dst, int rl, const f32x16& a0, const f32x16& a1) {
        #pragma unroll
        for (int q = 0; q < 4; ++q) {
            float4 v0 = {a0[4 * q], a0[4 * q + 1], a0[4 * q + 2], a0[4 * q + 3]};
            float4 v1 = {a1[4 * q], a1[4 * q + 1], a1[4 * q + 2], a1[4 * q + 3]};
            *(float4*)&dst[rl * LD + q * 8 + half * 4]      = v0;
            *(float4*)&dst[rl * LD + 32 + q * 8 + half * 4] = v1;
        }
    };

    // ---- phase 1: P2 (waves 0-2) and P1 (waves 3-5) GEMMs ----
    if (w < 6) {
        int mat, ntile, rowoff; float* dst;
        if (w < 3) { mat = 2; ntile = (w == 0) ? 0 : ((w == 1) ? 32 : 48); rowoff = -8; dst = P2s; }
        else       { mat = 1; ntile = (w == 3) ? 0 : ((w == 4) ? 32 : 40); rowoff = -4; dst = P1s; }
        f32x16 acc0 = {}, acc1 = {};
        gemm_accs(mat, rowoff, ntile + m31, acc0, acc1);
        scatter(dst, ntile + m31, acc0, acc1);
    }
    __syncthreads();

    // ---- phase 2: stencil1 (VALU, waves 0-5) || P0 GEMM (MFMA, waves 6-7) ----
    f32x16 pacc0 = {}, pacc1 = {};
    int prl = 0;
    if (tid < 384) {
        // stencil1: S = P1 + 2 L P2, in place on P1s, strips of 3
        const int st = tid >> 4, c0 = (tid & 15) << 2;
        const int r0 = st * 3;
        float4 win[11];
        #pragma unroll
        for (int l = 0; l < 11; ++l)
            win[l] = *(const float4*)&P2s[(r0 + l) * LD + c0];
        #pragma unroll
        for (int r = 0; r < 3; ++r) {
            const int sg = r0 + r;
            float4 vA = *(const float4*)&Vs[sg * 12];
            float4 vB = *(const float4*)&Vs[sg * 12 + 4];
            float v8 = Vs[sg * 12 + 8];
            const float vj[9] = {vA.x, vA.y, vA.z, vA.w, vB.x, vB.y, vB.z, vB.w, v8};
            float4 a = {0.f, 0.f, 0.f, 0.f};
            #pragma unroll
            for (int j = 0; j < 9; ++j) {
                float4 xv = win[r + j];
                a.x = fmaf(vj[j], xv.x, a.x); a.y = fmaf(vj[j], xv.y, a.y);
                a.z = fmaf(vj[j], xv.z, a.z); a.w = fmaf(vj[j], xv.w, a.w);
            }
            float4 p1 = *(const float4*)&P1s[sg * LD + c0];
            p1.x = fmaf(2.f, a.x, p1.x); p1.y = fmaf(2.f, a.y, p1.y);
            p1.z = fmaf(2.f, a.z, p1.z); p1.w = fmaf(2.f, a.w, p1.w);
            *(float4*)&P1s[sg * LD + c0] = p1;
        }
    } else {
        prl = ((w == 6) ? 0 : 32) + m31;
        gemm_accs(0, 0, prl, pacc0, pacc1);
    }
    __syncthreads();

    // ---- phase 3: P0 scatter into P2s (now dead) ----
    if (tid >= 384) scatter(P2s, prl, pacc0, pacc1);
    __syncthreads();

    // ---- phase 4: stencil2 + epilogue: Y = elu(P0 + L S + b) ----
    {
        const int est = tid >> 4, ecx = tid & 15;
        const int ey0 = est * 2, ec0 = ecx << 2;
        float4 win[10];
        #pragma unroll
        for (int l = 0; l < 10; ++l)
            win[l] = *(const float4*)&P1s[(ey0 + l) * LD + ec0];
        const float4 bb = *(const float4*)&bias[ec0];
        #pragma unroll
        for (int r = 0; r < 2; ++r) {
            const int y = ey0 + r;
            float4 vA = *(const float4*)&Vs[(y + 4) * 12];
            float4 vB = *(const float4*)&Vs[(y + 4) * 12 + 4];
            float v8 = Vs[(y + 4) * 12 + 8];
            const float vj[9] = {vA.x, vA.y, vA.z, vA.w, vB.x, vB.y, vB.z, vB.w, v8};
            float4 a = bb;
            #pragma unroll
            for (int j = 0; j < 9; ++j) {
                float4 xv = win[r + j];
                a.x = fmaf(vj[j], xv.x, a.x); a.y = fmaf(vj[j], xv.y, a.y);
                a.z = fmaf(vj[j], xv.z, a.z); a.w = fmaf(vj[j], xv.w, a.w);
            }
            float4 p0 = *(const float4*)&P2s[y * LD + ec0];
            float yv[4] = {a.x + p0.x, a.y + p0.y, a.z + p0.z, a.w + p0.w};
            ushort4 h, l;
            u16 hh;
            #pragma unroll
            for (int e = 0; e < 4; ++e)
                yv[e] = yv[e] > 0.f ? yv[e] : __expf(yv[e]) - 1.f;
            hh = bf16_rn(yv[0]); h.x = hh; l.x = bf16_rn(yv[0] - bf16_to_f(hh));
            hh = bf16_rn(yv[1]); h.y = hh; l.y = bf16_rn(yv[1] - bf16_to_f(hh));
            hh = bf16_rn(yv[2]); h.z = hh; l.z = bf16_rn(yv[2] - bf16_to_f(hh));
            hh = bf16_rn(yv[3]); h.w = hh; l.w = bf16_rn(yv[3] - bf16_to_f(hh));
            const int gy = n0 + y;
            size_t dsto = bplane + (size_t)(gy >> 5) * 2048 + (size_t)(ecx >> 1) * 256
                        + (size_t)(gy & 31) * 8 + (size_t)(ecx & 1) * 4;
            *(ushort4*)&Yh[dsto] = h;
            *(ushort4*)&Yl[dsto] = l;
        }
    }
}

// ---------------------------------------------------------------------------
// Last layer, 128 rows/block (verified R12) + W5 fragments pre-split into LDS
// once per block (bit-identical frag values; replaces 32 scalar W5 loads +
// ~200 conversion-VALU per GEMM wave with 8 conflict-free ds_read_b128).
// ---------------------------------------------------------------------------
__global__ __launch_bounds__(512, 4)
void cheb_last4(const u16* __restrict__ Xh, const u16* __restrict__ Xl,
                const float* __restrict__ vals,
                const float* __restrict__ W5, const float* __restrict__ b5,
                float* __restrict__ Y) {
    __shared__ alignas(16) float Pb[144 * 8];
    __shared__ alignas(16) float Sb[136 * 2];
    __shared__ alignas(16) float Vs[136 * 12];
    __shared__ alignas(16) u16 W5h[2048];
    __shared__ alignas(16) u16 W5l[2048];

    const int tid = threadIdx.x;
    const int n0 = blockIdx.x * 128;
    const int b  = blockIdx.y;
    const size_t bplane = (size_t)b * ((size_t)N_PIX * 64);

    for (int i = tid; i < 1224; i += 512) {
        int sr = i / 9, j = i - sr * 9;
        int g = (n0 - 4 + sr) & (N_PIX - 1);
        Vs[sr * 12 + j] = vals[(size_t)g * DEG + j];
    }
    // W5 frags: idx = s*512 + lane*8 + j; value for lane's (seg,o,k) as in the
    // verified in-loop construction: k = s*16 + (lane>>5)*8 + j.
    for (int i = tid; i < 2048; i += 512) {
        int j = i & 7, lane = (i >> 3) & 63, s = i >> 9;
        int m = lane & 31;
        float x = 0.f;
        if (m < 6) x = W5[((m >> 1) * 64 + s * 16 + ((lane >> 5) << 3) + j) * 2 + (m & 1)];
        u16 hh = bf16_rn(x);
        W5h[i] = hh;
        W5l[i] = bf16_rn(x - bf16_to_f(hh));
    }
    __syncthreads();

    {
        const int w = tid >> 6, lane = tid & 63;
        const int half = lane >> 5, m31 = lane & 31;
        if (w < 5) {
            const int ntile = (w == 4) ? 112 : w * 32;
            const int rl = ntile + m31;
            const int g = (n0 - 8 + rl) & (N_PIX - 1);
            const size_t bbase = bplane + (size_t)(g >> 5) * 2048 + (g & 31) * 8;
            f32x16 acc = {};
            #pragma unroll
            for (int s = 0; s < 4; ++s) {
                const size_t off = bbase + (size_t)(s * 2 + half) * 256;
                bf16x8 bh = *(const bf16x8*)&Xh[off];
                bf16x8 bl = *(const bf16x8*)&Xl[off];
                const int fi = s * 512 + lane * 8;
                bf16x8 ah = *(const bf16x8*)&W5h[fi];
                bf16x8 al = *(const bf16x8*)&W5l[fi];
                acc = __builtin_amdgcn_mfma_f32_32x32x16_bf16(al, bh, acc, 0, 0, 0);
                acc = __builtin_amdgcn_mfma_f32_32x32x16_bf16(ah, bl, acc, 0, 0, 0);
                acc = __builtin_amdgcn_mfma_f32_32x32x16_bf16(ah, bh, acc, 0, 0, 0);
            }
            if (half == 0) {
                float4 v = {acc[0], acc[1], acc[2], acc[3]};
                *(float4*)&Pb[rl * 8] = v;
            } else {
                Pb[rl * 8 + 4] = acc[0];
                Pb[rl * 8 + 5] = acc[1];
            }
        }
    }
    __syncthreads();

    if (tid < 272) {
        const int sg = tid >> 1, o = tid & 1;
        float q = 0.f;
        #pragma unroll
        for (int j = 0; j < DEG; ++j)
            q = fmaf(Vs[sg * 12 + j], Pb[(sg + j) * 8 + 4 + o], q);
        Sb[sg * 2 + o] = Pb[(sg + 4) * 8 + 2 + o] + 2.f * q;
    }
    __syncthreads();

    if (tid < 256) {
        const int y = tid >> 1, o = tid & 1;
        float q = 0.f;
        #pragma unroll
        for (int j = 0; j < DEG; ++j)
            q = fmaf(Vs[(y + 4) * 12 + j], Sb[(y + j) * 2 + o], q);
        float v = Pb[(y + 8) * 8 + o] - Pb[(y + 8) * 8 + 4 + o] + q + b5[o];
        Y[((size_t)b * N_PIX + n0 + y) * 2 + o] = v;
    }
}

extern "C" void kernel_launch(void* const* d_in, const int* in_sizes, int n_in,
                              void* d_out, int out_size, void* d_ws, size_t ws_size,
                              hipStream_t stream) {
    const float* x    = (const float*)d_in[0];
    const float* vals = (const float*)d_in[3];
    const float* W1 = (const float*)d_in[4];
    const float* b1 = (const float*)d_in[5];
    const float* W2 = (const float*)d_in[6];
    const float* b2 = (const float*)d_in[7];
    const float* W3 = (const float*)d_in[8];
    const float* b3 = (const float*)d_in[9];
    const float* W4 = (const float*)d_in[10];
    const float* b4 = (const float*)d_in[11];
    const float* W5 = (const float*)d_in[12];
    const float* b5 = (const float*)d_in[13];
    float* out = (float*)d_out;

    const size_t PL = (size_t)BATCH * N_PIX * 64;
    u16* Ah_g = (u16*)d_ws;
    u16* Al_g = Ah_g + PL;
    u16* Bh_g = Ah_g + 2 * PL;
    u16* Bl_g = Ah_g + 3 * PL;
    // d_out scratch: weight frags [0, 246 KiB) + Vpre at byte 262144
    // (1.57 MiB) -> 1.83 MiB < 2 MiB; all consumed before cheb_last4
    // overwrites d_out with Y.
    u16* wt = (u16*)d_out;
    float* vpre = (float*)((char*)d_out + 262144);

    dim3 grid(N_PIX / TILE, BATCH);
    prep_all<<<dim3(13, 16), dim3(256), 0, stream>>>(W1, W2, W3, W4, vals, wt, vpre);
    cheb_conv<true><<<grid, dim3(512), 0, stream>>>(x, nullptr, nullptr, vpre, wt, 73728, b1, Ah_g, Al_g);
    cheb_conv<false><<<grid, dim3(512), 0, stream>>>(nullptr, Ah_g, Al_g, vpre, wt, 0,     b2, Bh_g, Bl_g);
    cheb_conv<false><<<grid, dim3(512), 0, stream>>>(nullptr, Bh_g, Bl_g, vpre, wt, 24576, b3, Ah_g, Al_g);
    cheb_conv<false><<<grid, dim3(512), 0, stream>>>(nullptr, Ah_g, Al_g, vpre, wt, 49152, b4, Bh_g, Bl_g);
    cheb_last4<<<dim3(N_PIX / 128, BATCH), dim3(512), 0, stream>>>(Bh_g, Bl_g, vals, W5, b5, out);
}